// Round 16
// baseline (1217.449 us; speedup 1.0000x reference)
//
#include <hip/hip_runtime.h>
#include <hip/hip_fp16.h>

#define NPG 38
#define HEAD_BLK 256
#define SHIFT 13
#define SLICE (1 << SHIFT)        // 8192 nodes per dst-bucket (32KB LDS)
#define DBMAX 640                 // max dst buckets
#define NSB 8                     // src super-buckets
#define NB1 1024                  // blocks for P1a/P1b
#define P1_THR 512
#define CH 8192                   // records per P2 chunk
#define P2_THR 512
#define CGS 64                    // chunks per chunk-group (p2b/sum1)

typedef int      v4i __attribute__((ext_vector_type(4)));
typedef float    v4f __attribute__((ext_vector_type(4)));
typedef unsigned v2u __attribute__((ext_vector_type(2)));

static inline __device__ unsigned short f2h(float f) {
    return __half_as_ushort(__float2half(f));
}
static inline __device__ float h2f(unsigned short b) {
    return __half2float(__ushort_as_half(b));
}

// ---------------------------------------------------------------------------
// P1a: per-block per-super counts only (src read only; plain stores).
// ---------------------------------------------------------------------------
__global__ __launch_bounds__(P1_THR) void k_p1a(
    const int* __restrict__ src, int nquads, int qpb, int sbsz,
    int* __restrict__ histM8)          // [NSB][NB1]
{
    __shared__ int h8[NSB];
    const int tid = threadIdx.x;
    if (tid < NSB) h8[tid] = 0;
    __syncthreads();
    const int blk = blockIdx.x;
    const int q0 = blk * qpb;
    const int q1 = min(q0 + qpb, nquads);
    const v4i* s4 = (const v4i*)src;
    for (int q = q0 + tid; q < q1; q += P1_THR) {
        v4i s = __builtin_nontemporal_load(s4 + q);
        atomicAdd(&h8[s.x / sbsz], 1);
        atomicAdd(&h8[s.y / sbsz], 1);
        atomicAdd(&h8[s.z / sbsz], 1);
        atomicAdd(&h8[s.w / sbsz], 1);
    }
    __syncthreads();
    if (tid < NSB) histM8[tid * NB1 + blk] = h8[tid];
}

// ---------------------------------------------------------------------------
// scanM: histM8 -> absolute per-(super,block) emit offsets (in place) + sseg.
// ---------------------------------------------------------------------------
__global__ __launch_bounds__(512) void k_scanM(
    int* __restrict__ histM8, int* __restrict__ sseg)
{
    __shared__ int stot[NSB];
    __shared__ int sbase[NSB + 1];
    const int tid = threadIdx.x;
    const int wid = tid >> 6, lane = tid & 63;

    const int base = wid * NB1 + lane * (NB1 / 64);
    int vals[NB1 / 64];
    int s = 0;
    #pragma unroll
    for (int k = 0; k < NB1 / 64; ++k) { vals[k] = s; s += histM8[base + k]; }
    int excl = s;
    #pragma unroll
    for (int d = 1; d < 64; d <<= 1) {
        int t = __shfl_up(excl, d, 64);
        if (lane >= d) excl += t;
    }
    excl -= s;
    if (lane == 63) stot[wid] = excl + s;
    __syncthreads();
    if (tid == 0) {
        int run = 0;
        for (int i = 0; i < NSB; ++i) { sbase[i] = run; run += stot[i]; }
        sbase[NSB] = run;
    }
    __syncthreads();
    const int b0 = sbase[wid] + excl;
    #pragma unroll
    for (int k = 0; k < NB1 / 64; ++k) histM8[base + k] = vals[k] + b0;
    if (tid < NSB + 1) sseg[tid] = sbase[tid];
}

// ---------------------------------------------------------------------------
// P1b: re-read edges, emit records at precomputed absolute offsets.
// Record = 8B: lo = (src_local[15:0]<<16)|fp16(theta), hi = dst|(sl>>16)<<23
// ---------------------------------------------------------------------------
__global__ __launch_bounds__(P1_THR) void k_p1b(
    const int* __restrict__ src, const int* __restrict__ dst,
    const float* __restrict__ ea,
    const float* __restrict__ w_edge, const float* __restrict__ b_edge,
    int nquads, int qpb, int sbsz,
    const int* __restrict__ histM8,
    v2u* __restrict__ recs)
{
    __shared__ int cur8[NSB];
    const int blk = blockIdx.x;
    if (threadIdx.x < NSB) cur8[threadIdx.x] = histM8[threadIdx.x * NB1 + blk];
    __syncthreads();
    const int q0 = blk * qpb;
    const int q1 = min(q0 + qpb, nquads);
    const float we = w_edge[0], be = b_edge[0];
    const v4i* s4 = (const v4i*)src;
    const v4i* d4 = (const v4i*)dst;
    const v4f* e4 = (const v4f*)ea;
    for (int q = q0 + threadIdx.x; q < q1; q += P1_THR) {
        v4i s = __builtin_nontemporal_load(s4 + q);
        v4i d = __builtin_nontemporal_load(d4 + q);
        v4f e = __builtin_nontemporal_load(e4 + q);
        #pragma unroll
        for (int k = 0; k < 4; ++k) {
            int sv = (k == 0) ? s.x : (k == 1) ? s.y : (k == 2) ? s.z : s.w;
            int dv = (k == 0) ? d.x : (k == 1) ? d.y : (k == 2) ? d.z : d.w;
            float ev = (k == 0) ? e.x : (k == 1) ? e.y : (k == 2) ? e.z : e.w;
            int sb = sv / sbsz;
            int sl = sv - sb * sbsz;
            unsigned short tb = f2h(fmaf(ev, we, be));
            int p = atomicAdd(&cur8[sb], 1);       // LDS-only
            v2u r;
            r.x = ((unsigned)(sl & 0xFFFF) << 16) | (unsigned)tb;
            r.y = (unsigned)dv | ((unsigned)(sl >> 16) << 23);
            recs[p] = r;
        }
    }
}

// ---------------------------------------------------------------------------
// P2: GLOBAL chunking; per-record super resolved against sseg. XCD swizzle.
// LDS counting sort -> fixed slot pairs[(size_t)j*CH] + u16 offset table.
// ---------------------------------------------------------------------------
__global__ __launch_bounds__(P2_THR) void k_p2(
    const v2u* __restrict__ recs, const float* __restrict__ x,
    const int* __restrict__ sseg, int sbsz, int DB, int NCH, int bpx, int E,
    unsigned short* __restrict__ ofsT, unsigned* __restrict__ pairs)
{
    __shared__ __align__(16) unsigned pairbuf[CH];  // 32768 B
    __shared__ int hD[DBMAX];
    __shared__ int lofs[DBMAX];
    __shared__ int lcur[DBMAX];
    __shared__ int sS[NSB + 1];

    const int jraw = blockIdx.x;
    const int j = (jraw & 7) * bpx + (jraw >> 3);   // XCD-affine, bijective
    if (j >= NCH) return;
    const int start = j * CH;
    const int n = min(CH, E - start);
    const int tid = threadIdx.x;
    const int wid = tid >> 6, lane = tid & 63;

    if (tid < NSB + 1) sS[tid] = sseg[tid];
    for (int i = tid; i < DBMAX; i += P2_THR) hD[i] = 0;
    __syncthreads();

    // pass A: histogram, 8-deep batches
    #pragma unroll
    for (int half = 0; half < CH / (8 * P2_THR); ++half) {
        unsigned bk[8];
        #pragma unroll
        for (int k = 0; k < 8; ++k) {
            int idx = tid + (half * 8 + k) * P2_THR;
            bk[k] = (idx < n) ? ((recs[start + idx].y & 0x7FFFFFu) >> SHIFT)
                              : 0xFFFFu;
        }
        #pragma unroll
        for (int k = 0; k < 8; ++k)
            if (bk[k] != 0xFFFFu) atomicAdd(&hD[bk[k]], 1);
    }
    __syncthreads();

    // wave 0: exclusive scan of hD -> lofs (10 elems/lane)
    if (wid == 0) {
        const int base = lane * (DBMAX / 64);
        int vals[DBMAX / 64];
        int s = 0;
        #pragma unroll
        for (int k = 0; k < DBMAX / 64; ++k) { vals[k] = s; s += hD[base + k]; }
        int excl = s;
        #pragma unroll
        for (int d = 1; d < 64; d <<= 1) {
            int t = __shfl_up(excl, d, 64);
            if (lane >= d) excl += t;
        }
        excl -= s;
        #pragma unroll
        for (int k = 0; k < DBMAX / 64; ++k) lofs[base + k] = vals[k] + excl;
    }
    __syncthreads();

    // offset table write + local cursors
    const size_t tbase = (size_t)j * (DBMAX + 1);
    for (int b = tid; b < DB; b += P2_THR) {
        lcur[b] = lofs[b];
        ofsT[tbase + b] = (unsigned short)lofs[b];
    }
    if (tid == 0) ofsT[tbase + DB] = (unsigned short)n;
    __syncthreads();

    // pass B: 8-deep batched load + gather (x slice L2-hot), LDS scatter-sort
    #pragma unroll
    for (int half = 0; half < CH / (8 * P2_THR); ++half) {
        v2u r[8];
        #pragma unroll
        for (int k = 0; k < 8; ++k) {
            int idx = tid + (half * 8 + k) * P2_THR;
            if (idx < n) r[k] = recs[start + idx];
            else { r[k].x = 0u; r[k].y = 0u; }
        }
        float xv[8];
        #pragma unroll
        for (int k = 0; k < 8; ++k) {
            int idx = tid + (half * 8 + k) * P2_THR;
            int gp = start + min(idx, n - 1);
            int sbr = 0;
            #pragma unroll
            for (int s = 1; s < NSB; ++s) sbr += (gp >= sS[s]);
            int sl = (int)(r[k].x >> 16) | (int)((r[k].y >> 23) << 16);
            xv[k] = x[(size_t)sbr * sbsz + sl];
        }
        #pragma unroll
        for (int k = 0; k < 8; ++k) {
            int idx = tid + (half * 8 + k) * P2_THR;
            if (idx < n) {
                unsigned d = r[k].y & 0x7FFFFFu;
                float m = xv[k] * h2f((unsigned short)(r[k].x & 0xFFFFu));
                int li = atomicAdd(&lcur[d >> SHIFT], 1);
                pairbuf[li] = ((d & (SLICE - 1)) << 16) | (unsigned)f2h(m);
            }
        }
    }
    __syncthreads();

    // pass C: fully-coalesced uint4 dump into the chunk's fixed slot
    const size_t pbase = (size_t)j * CH;
    uint4* out4 = reinterpret_cast<uint4*>(pairs + pbase);
    const uint4* pb4 = reinterpret_cast<const uint4*>(pairbuf);
    #pragma unroll
    for (int i = 0; i < CH / 4 / P2_THR; ++i)
        out4[tid + i * P2_THR] = pb4[tid + i * P2_THR];
}

// ---------------------------------------------------------------------------
// sum1: per-(chunk-group, bucket) run-length totals. Coalesced u16 reads.
// ---------------------------------------------------------------------------
__global__ __launch_bounds__(1024) void k_sum1(
    const unsigned short* __restrict__ ofsT,
    int NCH, int DB, int* __restrict__ partial)  // [ncg][DB]
{
    const int cg = blockIdx.x;
    const int j0 = cg * CGS;
    const int jn = min(CGS, NCH - j0);
    const int b = threadIdx.x;
    if (b >= DB) return;
    int acc = 0;
    for (int k = 0; k < jn; ++k) {
        size_t tb = (size_t)(j0 + k) * (DBMAX + 1);
        acc += (int)ofsT[tb + b + 1] - (int)ofsT[tb + b];
    }
    partial[(size_t)cg * DB + b] = acc;
}

// ---------------------------------------------------------------------------
// sum2: scan partials -> groupbase[cg][b] (absolute output offsets) + bbaseD.
// ---------------------------------------------------------------------------
__global__ __launch_bounds__(1024) void k_sum2(
    const int* __restrict__ partial, int ncg, int DB,
    int* __restrict__ groupbase, int* __restrict__ bbaseD)
{
    __shared__ int btot[DBMAX];
    __shared__ int bofs[DBMAX];
    const int tid = threadIdx.x;
    const int wid = tid >> 6, lane = tid & 63;
    for (int i = tid; i < DBMAX; i += 1024) btot[i] = 0;
    __syncthreads();
    if (tid < DB) {
        int run = 0;
        for (int cg = 0; cg < ncg; ++cg) {
            int t = partial[(size_t)cg * DB + tid];
            groupbase[(size_t)cg * DB + tid] = run;
            run += t;
        }
        btot[tid] = run;
    }
    __syncthreads();
    if (wid == 0) {
        const int base = lane * (DBMAX / 64);
        int vals[DBMAX / 64];
        int s = 0;
        #pragma unroll
        for (int k = 0; k < DBMAX / 64; ++k) { vals[k] = s; s += btot[base + k]; }
        int excl = s;
        #pragma unroll
        for (int d = 1; d < 64; d <<= 1) {
            int t = __shfl_up(excl, d, 64);
            if (lane >= d) excl += t;
        }
        excl -= s;
        #pragma unroll
        for (int k = 0; k < DBMAX / 64; ++k) bofs[base + k] = vals[k] + excl;
    }
    __syncthreads();
    if (tid < DB) {
        int bb = bofs[tid];
        bbaseD[tid] = bb;
        for (int cg = 0; cg < ncg; ++cg)
            groupbase[(size_t)cg * DB + tid] += bb;
    }
    if (tid == DB - 1) bbaseD[DB] = bofs[tid] + btot[tid];
}

// ---------------------------------------------------------------------------
// P2b: corner-turn copy. Block = (bucket-group of ~76, chunk-group of 64).
// Each wave owns buckets (stride 16) and walks 64 chunks with 8-deep
// pipelined run copies into a register-cursor contiguous output stream.
// No barriers, no LDS, no atomics.
// ---------------------------------------------------------------------------
__global__ __launch_bounds__(1024) void k_p2b(
    const unsigned* __restrict__ pairs,
    const unsigned short* __restrict__ ofsT,
    const int* __restrict__ groupbase,   // [ncg][DB]
    int NCH, int DB, int ncg,
    unsigned* __restrict__ pairs2)
{
    const int g  = blockIdx.x & 7;
    const int cg = blockIdx.x >> 3;
    if (cg >= ncg) return;
    const int bpb = (DB + 7) >> 3;
    const int b0 = g * bpb;
    const int b1 = min(b0 + bpb, DB);
    const int j0 = cg * CGS;
    const int jn = min(CGS, NCH - j0);
    const int wid = threadIdx.x >> 6, lane = threadIdx.x & 63;

    for (int b = b0 + wid; b < b1; b += 16) {
        int cur = groupbase[(size_t)cg * DB + b];
        int o0 = 0, len = 0;
        if (lane < jn) {
            size_t tb = (size_t)(j0 + lane) * (DBMAX + 1);
            o0 = ofsT[tb + b];
            len = (int)ofsT[tb + b + 1] - o0;
        }
        for (int k = 0; k < jn; k += 8) {
            int ro[8], rl[8], rc[8];
            int c = cur;
            #pragma unroll
            for (int u = 0; u < 8; ++u) {
                int l = __shfl(len, k + u, 64);
                ro[u] = __shfl(o0, k + u, 64);
                rl[u] = (k + u < jn) ? l : 0;
                rc[u] = c; c += rl[u];
            }
            unsigned v[8];
            #pragma unroll
            for (int u = 0; u < 8; ++u)
                if (lane < rl[u])
                    v[u] = pairs[(size_t)(j0 + k + u) * CH + ro[u] + lane];
            #pragma unroll
            for (int u = 0; u < 8; ++u)
                if (lane < rl[u]) pairs2[rc[u] + lane] = v[u];
            // tail: runs longer than 64 (rare)
            #pragma unroll
            for (int u = 0; u < 8; ++u)
                for (int t = lane + 64; t < rl[u]; t += 64)
                    pairs2[rc[u] + t] =
                        pairs[(size_t)(j0 + k + u) * CH + ro[u] + t];
            cur = c;
        }
    }
}

// ---------------------------------------------------------------------------
// binB_lin: per-bucket linear read of contiguous pairs2 segment + LDS
// accumulate + fused root transform -> nodes.
// ---------------------------------------------------------------------------
__global__ __launch_bounds__(1024) void k_binB_lin(
    const unsigned* __restrict__ pairs,
    const int* __restrict__ bbaseD,
    const float* __restrict__ x,
    const float* __restrict__ w_root, const float* __restrict__ b_conv,
    float* __restrict__ nodes, int N)
{
    __shared__ float slice[SLICE];
    const int b = blockIdx.x;
    for (int i = threadIdx.x; i < SLICE; i += 1024) slice[i] = 0.0f;
    __syncthreads();
    const int p0 = bbaseD[b];
    const int p1 = bbaseD[b + 1];
    for (int i = p0 + threadIdx.x; i < p1; i += 1024) {
        unsigned p = __builtin_nontemporal_load(pairs + i);
        atomicAdd(&slice[p >> 16], h2f((unsigned short)(p & 0xFFFFu)));
    }
    __syncthreads();
    const float wr = w_root[0], bc = b_conv[0];
    const int gbase = b << SHIFT;
    for (int i = threadIdx.x; i < SLICE; i += 1024) {
        int gi = gbase + i;
        if (gi < N) nodes[gi] = slice[i] + fmaf(__builtin_nontemporal_load(x + gi), wr, bc);
    }
}

// ---------------------------------------------------------------------------
// Mid-fallback: dst-binning with gather (reservation-based)
// ---------------------------------------------------------------------------
__global__ __launch_bounds__(512) void k_count_mid(
    const int* __restrict__ dst, int nquads, int qpb, int DB,
    int* __restrict__ gcntD)
{
    __shared__ int hD[DBMAX];
    for (int i = threadIdx.x; i < DB; i += 512) hD[i] = 0;
    __syncthreads();
    const int q0 = blockIdx.x * qpb;
    const int q1 = min(q0 + qpb, nquads);
    const v4i* d4 = (const v4i*)dst;
    for (int q = q0 + threadIdx.x; q < q1; q += 512) {
        v4i d = __builtin_nontemporal_load(d4 + q);
        atomicAdd(&hD[d.x >> SHIFT], 1);
        atomicAdd(&hD[d.y >> SHIFT], 1);
        atomicAdd(&hD[d.z >> SHIFT], 1);
        atomicAdd(&hD[d.w >> SHIFT], 1);
    }
    __syncthreads();
    for (int i = threadIdx.x; i < DB; i += 512)
        if (hD[i]) atomicAdd(&gcntD[i], hD[i]);
}

__global__ void k_scanD(const int* __restrict__ gcntD, int DB,
                        int* __restrict__ bbaseD, int* __restrict__ gcurD)
{
    if (threadIdx.x == 0 && blockIdx.x == 0) {
        int run = 0;
        for (int i = 0; i < DB; ++i) { bbaseD[i] = run; gcurD[i] = run; run += gcntD[i]; }
        bbaseD[DB] = run;
    }
}

__global__ __launch_bounds__(512) void k_binA_resv(
    const float* __restrict__ x,
    const int* __restrict__ src, const int* __restrict__ dst,
    const float* __restrict__ ea,
    const float* __restrict__ w_edge, const float* __restrict__ b_edge,
    int nquads, int qpb, int DB,
    int* __restrict__ gcurD, unsigned* __restrict__ pairs)
{
    __shared__ int hD[DBMAX];
    __shared__ int cur[DBMAX];
    const int q0 = blockIdx.x * qpb;
    const int q1 = min(q0 + qpb, nquads);
    for (int i = threadIdx.x; i < DB; i += 512) hD[i] = 0;
    __syncthreads();
    const v4i* s4 = (const v4i*)src;
    const v4i* d4 = (const v4i*)dst;
    const v4f* e4 = (const v4f*)ea;
    for (int q = q0 + threadIdx.x; q < q1; q += 512) {
        v4i d = d4[q];
        atomicAdd(&hD[d.x >> SHIFT], 1);
        atomicAdd(&hD[d.y >> SHIFT], 1);
        atomicAdd(&hD[d.z >> SHIFT], 1);
        atomicAdd(&hD[d.w >> SHIFT], 1);
    }
    __syncthreads();
    for (int i = threadIdx.x; i < DB; i += 512) {
        int cnt = hD[i];
        cur[i] = cnt ? atomicAdd(&gcurD[i], cnt) : 0;
    }
    __syncthreads();
    const float we = w_edge[0], be = b_edge[0];
    for (int q = q0 + threadIdx.x; q < q1; q += 512) {
        v4i s = __builtin_nontemporal_load(s4 + q);
        v4i d = d4[q];
        v4f e = __builtin_nontemporal_load(e4 + q);
        #pragma unroll
        for (int k = 0; k < 4; ++k) {
            int sv = (k == 0) ? s.x : (k == 1) ? s.y : (k == 2) ? s.z : s.w;
            unsigned dv = (unsigned)((k == 0) ? d.x : (k == 1) ? d.y : (k == 2) ? d.z : d.w);
            float ev = (k == 0) ? e.x : (k == 1) ? e.y : (k == 2) ? e.z : e.w;
            float m = x[sv] * fmaf(ev, we, be);
            int p = atomicAdd(&cur[dv >> SHIFT], 1);
            pairs[p] = ((dv & (SLICE - 1)) << 16) | (unsigned)f2h(m);
        }
    }
}

// ---------------------------------------------------------------------------
// Bottom fallback: global atomics
// ---------------------------------------------------------------------------
__global__ __launch_bounds__(256) void edge_kernel_atomic(
    const float* __restrict__ x,
    const int*   __restrict__ src, const int* __restrict__ dst,
    const float* __restrict__ ea,
    const float* __restrict__ w_edge, const float* __restrict__ b_edge,
    float* __restrict__ agg, int E)
{
    const float we = w_edge[0], be = b_edge[0];
    int tid = blockIdx.x * blockDim.x + threadIdx.x;
    int stride = gridDim.x * blockDim.x;
    for (int i = tid; i < E; i += stride)
        atomicAdd(&agg[dst[i]], x[src[i]] * fmaf(ea[i], we, be));
}

__global__ __launch_bounds__(256) void finalize_nodes(
    const float* __restrict__ x, const float* __restrict__ agg,
    const float* __restrict__ w_root, const float* __restrict__ b_conv,
    float* __restrict__ nodes, int N)
{
    const float wr = w_root[0], bc = b_conv[0];
    int i = blockIdx.x * blockDim.x + threadIdx.x;
    int stride = gridDim.x * blockDim.x;
    for (; i < N; i += stride) nodes[i] = agg[i] + fmaf(x[i], wr, bc);
}

// ---------------------------------------------------------------------------
// Head MLP over per-graph node vectors + softmax
// ---------------------------------------------------------------------------
__global__ __launch_bounds__(HEAD_BLK) void head_kernel(
    const float* __restrict__ nodes,
    const float* __restrict__ W1, const float* __restrict__ b1,
    const float* __restrict__ W2, const float* __restrict__ b2,
    const float* __restrict__ W3, const float* __restrict__ b3,
    float* __restrict__ out, int G)
{
    __shared__ float s_nodes[HEAD_BLK * NPG];   // 38912 B
    __shared__ float s_W1[NPG * 4];
    __shared__ float s_W2[4 * 4];
    __shared__ float s_W3[4 * 12];
    __shared__ float s_b1[4];
    __shared__ float s_b2[4];
    __shared__ float s_b3[12];

    const int tid = threadIdx.x;
    if (tid < NPG * 4) s_W1[tid] = W1[tid];
    if (tid >= 160 && tid < 176) s_W2[tid - 160] = W2[tid - 160];
    if (tid >= 176 && tid < 224) s_W3[tid - 176] = W3[tid - 176];
    if (tid >= 224 && tid < 228) s_b1[tid - 224] = b1[tid - 224];
    if (tid >= 228 && tid < 232) s_b2[tid - 228] = b2[tid - 228];
    if (tid >= 232 && tid < 244) s_b3[tid - 232] = b3[tid - 232];

    const int g0 = blockIdx.x * HEAD_BLK;
    const size_t ebase = (size_t)g0 * NPG;
    const int nelem = HEAD_BLK * NPG;
    const int avail = min(nelem, (G - g0) * NPG);
    for (int i = tid; i < avail; i += HEAD_BLK) s_nodes[i] = nodes[ebase + i];
    __syncthreads();

    const int g = g0 + tid;
    if (g >= G) return;
    const float* nd = &s_nodes[tid * NPG];

    float h1[4];
    #pragma unroll
    for (int k = 0; k < 4; ++k) h1[k] = s_b1[k];
    #pragma unroll
    for (int j = 0; j < NPG; ++j) {
        const float nj = nd[j];
        #pragma unroll
        for (int k = 0; k < 4; ++k) h1[k] = fmaf(nj, s_W1[j * 4 + k], h1[k]);
    }
    #pragma unroll
    for (int k = 0; k < 4; ++k) h1[k] = h1[k] >= 0.0f ? h1[k] : 0.01f * h1[k];

    float h2[4];
    #pragma unroll
    for (int k = 0; k < 4; ++k) {
        float a = s_b2[k];
        #pragma unroll
        for (int j = 0; j < 4; ++j) a = fmaf(h1[j], s_W2[j * 4 + k], a);
        h2[k] = a >= 0.0f ? a : 0.01f * a;
    }

    float h3[12];
    #pragma unroll
    for (int k = 0; k < 12; ++k) {
        float a = s_b3[k];
        #pragma unroll
        for (int j = 0; j < 4; ++j) a = fmaf(h2[j], s_W3[j * 12 + k], a);
        h3[k] = a >= 0.0f ? a : 0.01f * a;
    }

    float m = h3[0];
    #pragma unroll
    for (int k = 1; k < 12; ++k) m = fmaxf(m, h3[k]);
    float sum = 0.0f;
    #pragma unroll
    for (int k = 0; k < 12; ++k) { h3[k] = expf(h3[k] - m); sum += h3[k]; }
    const float inv = 1.0f / sum;

    float4* o = reinterpret_cast<float4*>(out + (size_t)g * 12);
    o[0] = make_float4(h3[0] * inv, h3[1] * inv, h3[2]  * inv, h3[3]  * inv);
    o[1] = make_float4(h3[4] * inv, h3[5] * inv, h3[6]  * inv, h3[7]  * inv);
    o[2] = make_float4(h3[8] * inv, h3[9] * inv, h3[10] * inv, h3[11] * inv);
}

extern "C" void kernel_launch(void* const* d_in, const int* in_sizes, int n_in,
                              void* d_out, int out_size, void* d_ws, size_t ws_size,
                              hipStream_t stream)
{
    const float* x      = (const float*)d_in[0];
    const int*   eidx   = (const int*)  d_in[1];
    const float* ea     = (const float*)d_in[2];
    const float* w_edge = (const float*)d_in[3];
    const float* b_edge = (const float*)d_in[4];
    const float* w_root = (const float*)d_in[5];
    const float* b_conv = (const float*)d_in[6];
    const float* W1 = (const float*)d_in[7];
    const float* b1 = (const float*)d_in[8];
    const float* W2 = (const float*)d_in[9];
    const float* b2 = (const float*)d_in[10];
    const float* W3 = (const float*)d_in[11];
    const float* b3 = (const float*)d_in[12];
    float* out = (float*)d_out;

    const int N = in_sizes[0];
    const int E = in_sizes[2];
    const int G = N / NPG;
    const int* src = eidx;
    const int* dst = eidx + E;
    const int nquads = E / 4;
    const int DB = (N + SLICE - 1) >> SHIFT;

    const int hblocks = (G + HEAD_BLK - 1) / HEAD_BLK;
    char* ws = (char*)d_ws;

    const bool quadok = (E % 4) == 0 && DB <= DBMAX && DB >= 1;
    const int  sbsz   = (N % NSB == 0) ? (N / NSB) : 0;

    const int NCH = (E + CH - 1) / CH;            // global chunk count
    const int bpx = (NCH + 7) / 8;
    const int ncg = (NCH + CGS - 1) / CGS;        // chunk-groups

    // meta ints: histM8[NSB*NB1] | sseg[NSB+1] | gcntD[DBMAX] | gcurD[DBMAX] |
    //            bbaseD[DBMAX+1] | partial[ncg*DBMAX] | groupbase[ncg*DBMAX]
    const size_t META_INTS = (size_t)NSB * NB1 + (NSB + 1) + DBMAX + DBMAX
                           + (DBMAX + 1) + 2 * (size_t)ncg * DBMAX;

    // v6 layout: recs (E*8, later reused as pairs2) | pairs (NCH*CH*4) |
    //            ofsT (NCH*(DBMAX+1)*2) | nodes (N*4) | meta
    size_t off_pairs = (size_t)E * 8;
    size_t sz_pairs  = (size_t)NCH * CH * 4;
    size_t off_ofsT  = off_pairs + sz_pairs;
    size_t sz_ofsT   = ((size_t)NCH * (DBMAX + 1) * 2 + 15) & ~(size_t)15;
    size_t off_nodes = off_ofsT + sz_ofsT;
    size_t off_meta  = off_nodes + (size_t)N * 4;
    size_t need_v6   = off_meta + META_INTS * 4;

    // mid layout: pairs (E*4) | nodes | meta
    size_t off_nodes_mid = (size_t)E * 4;
    size_t off_meta_mid  = off_nodes_mid + (size_t)N * 4;
    size_t need_mid      = off_meta_mid + META_INTS * 4;

    if (quadok && sbsz > 0 && need_v6 <= ws_size) {
        v2u*            recs   = (v2u*)ws;
        unsigned*       pairs2 = (unsigned*)ws;   // aliases recs (dead after P2)
        unsigned*       pairs  = (unsigned*)(ws + off_pairs);
        unsigned short* ofsT   = (unsigned short*)(ws + off_ofsT);
        float*          nodes  = (float*)(ws + off_nodes);
        int*            meta   = (int*)(ws + off_meta);
        int* histM8    = meta;
        int* sseg      = histM8 + NSB * NB1;
        int* bbaseD    = sseg + (NSB + 1) + DBMAX + DBMAX;
        int* partial   = bbaseD + (DBMAX + 1);
        int* groupbase = partial + (size_t)ncg * DBMAX;

        const int qpb = (nquads + NB1 - 1) / NB1;
        k_p1a<<<NB1, P1_THR, 0, stream>>>(src, nquads, qpb, sbsz, histM8);
        k_scanM<<<1, 512, 0, stream>>>(histM8, sseg);
        k_p1b<<<NB1, P1_THR, 0, stream>>>(src, dst, ea, w_edge, b_edge,
                                          nquads, qpb, sbsz, histM8, recs);
        k_p2<<<8 * bpx, P2_THR, 0, stream>>>(recs, x, sseg, sbsz, DB, NCH, bpx,
                                             E, ofsT, pairs);
        k_sum1<<<ncg, 1024, 0, stream>>>(ofsT, NCH, DB, partial);
        k_sum2<<<1, 1024, 0, stream>>>(partial, ncg, DB, groupbase, bbaseD);
        k_p2b<<<8 * ncg, 1024, 0, stream>>>(pairs, ofsT, groupbase, NCH, DB,
                                            ncg, pairs2);
        k_binB_lin<<<DB, 1024, 0, stream>>>(pairs2, bbaseD, x, w_root, b_conv,
                                            nodes, N);
        head_kernel<<<hblocks, HEAD_BLK, 0, stream>>>(nodes, W1, b1, W2, b2,
                                                      W3, b3, out, G);
    } else if (quadok && need_mid <= ws_size) {
        unsigned* pairs = (unsigned*)ws;
        float*    nodes = (float*)(ws + off_nodes_mid);
        int*      meta  = (int*)(ws + off_meta_mid);
        int* gcntD  = meta + NSB * NB1 + (NSB + 1);
        int* gcurD  = gcntD + DBMAX;
        int* bbaseD = gcurD + DBMAX;

        hipMemsetAsync(gcntD, 0, DBMAX * sizeof(int), stream);
        const int NBm = 2048;
        const int qpbm = (nquads + NBm - 1) / NBm;
        k_count_mid<<<NBm, 512, 0, stream>>>(dst, nquads, qpbm, DB, gcntD);
        k_scanD<<<1, 64, 0, stream>>>(gcntD, DB, bbaseD, gcurD);
        k_binA_resv<<<NBm, 512, 0, stream>>>(x, src, dst, ea, w_edge, b_edge,
                                             nquads, qpbm, DB, gcurD, pairs);
        k_binB_lin<<<DB, 1024, 0, stream>>>(pairs, bbaseD, x, w_root, b_conv,
                                            nodes, N);
        head_kernel<<<hblocks, HEAD_BLK, 0, stream>>>(nodes, W1, b1, W2, b2,
                                                      W3, b3, out, G);
    } else {
        float* agg   = (float*)d_ws;
        float* nodes = agg + N;
        hipMemsetAsync(agg, 0, (size_t)N * sizeof(float), stream);
        edge_kernel_atomic<<<2048, 256, 0, stream>>>(x, src, dst, ea, w_edge,
                                                     b_edge, agg, E);
        finalize_nodes<<<2048, 256, 0, stream>>>(x, agg, w_root, b_conv, nodes, N);
        head_kernel<<<hblocks, HEAD_BLK, 0, stream>>>(nodes, W1, b1, W2, b2,
                                                      W3, b3, out, G);
    }
}

// Round 17
// 1159.551 us; speedup vs baseline: 1.0499x; 1.0499x over previous
//
#include <hip/hip_runtime.h>
#include <hip/hip_fp16.h>

#define NPG 38
#define HEAD_BLK 256
#define SHIFT 14
#define SLICE (1 << SHIFT)        // 16384 nodes per dst-bucket (64KB LDS in binB)
#define DBMAX 320                 // max dst buckets
#define NSB 8                     // src super-buckets
#define NB1 1024                  // blocks for P1a/P1b
#define P1_THR 512
#define CH 8192                   // records per P2 chunk
#define P2_THR 512
#define BB_THR 1024
#define BB_NW (BB_THR / 64)       // 16 waves
#define BB_PH 1024                // chunks staged per binB phase

typedef int      v4i __attribute__((ext_vector_type(4)));
typedef float    v4f __attribute__((ext_vector_type(4)));
typedef unsigned v2u __attribute__((ext_vector_type(2)));

static inline __device__ unsigned short f2h(float f) {
    return __half_as_ushort(__float2half(f));
}
static inline __device__ float h2f(unsigned short b) {
    return __half2float(__ushort_as_half(b));
}

// ---------------------------------------------------------------------------
// P1a: per-block per-super counts only (src read only; plain stores).
// ---------------------------------------------------------------------------
__global__ __launch_bounds__(P1_THR) void k_p1a(
    const int* __restrict__ src, int nquads, int qpb, int sbsz,
    int* __restrict__ histM8)          // [NSB][NB1]
{
    __shared__ int h8[NSB];
    const int tid = threadIdx.x;
    if (tid < NSB) h8[tid] = 0;
    __syncthreads();
    const int blk = blockIdx.x;
    const int q0 = blk * qpb;
    const int q1 = min(q0 + qpb, nquads);
    const v4i* s4 = (const v4i*)src;
    for (int q = q0 + tid; q < q1; q += P1_THR) {
        v4i s = __builtin_nontemporal_load(s4 + q);
        atomicAdd(&h8[s.x / sbsz], 1);
        atomicAdd(&h8[s.y / sbsz], 1);
        atomicAdd(&h8[s.z / sbsz], 1);
        atomicAdd(&h8[s.w / sbsz], 1);
    }
    __syncthreads();
    if (tid < NSB) histM8[tid * NB1 + blk] = h8[tid];
}

// ---------------------------------------------------------------------------
// scanM: histM8 -> absolute per-(super,block) emit offsets (in place) + sseg.
// ---------------------------------------------------------------------------
__global__ __launch_bounds__(512) void k_scanM(
    int* __restrict__ histM8, int* __restrict__ sseg)
{
    __shared__ int stot[NSB];
    __shared__ int sbase[NSB + 1];
    const int tid = threadIdx.x;
    const int wid = tid >> 6, lane = tid & 63;

    const int base = wid * NB1 + lane * (NB1 / 64);
    int vals[NB1 / 64];
    int s = 0;
    #pragma unroll
    for (int k = 0; k < NB1 / 64; ++k) { vals[k] = s; s += histM8[base + k]; }
    int excl = s;
    #pragma unroll
    for (int d = 1; d < 64; d <<= 1) {
        int t = __shfl_up(excl, d, 64);
        if (lane >= d) excl += t;
    }
    excl -= s;
    if (lane == 63) stot[wid] = excl + s;
    __syncthreads();
    if (tid == 0) {
        int run = 0;
        for (int i = 0; i < NSB; ++i) { sbase[i] = run; run += stot[i]; }
        sbase[NSB] = run;
    }
    __syncthreads();
    const int b0 = sbase[wid] + excl;
    #pragma unroll
    for (int k = 0; k < NB1 / 64; ++k) histM8[base + k] = vals[k] + b0;
    if (tid < NSB + 1) sseg[tid] = sbase[tid];
}

// ---------------------------------------------------------------------------
// P1b: re-read edges, emit records at precomputed absolute offsets.
// Record = 8B: lo = (src_local[15:0]<<16)|fp16(theta), hi = dst|(sl>>16)<<23
// ---------------------------------------------------------------------------
__global__ __launch_bounds__(P1_THR) void k_p1b(
    const int* __restrict__ src, const int* __restrict__ dst,
    const float* __restrict__ ea,
    const float* __restrict__ w_edge, const float* __restrict__ b_edge,
    int nquads, int qpb, int sbsz,
    const int* __restrict__ histM8,
    v2u* __restrict__ recs)
{
    __shared__ int cur8[NSB];
    const int blk = blockIdx.x;
    if (threadIdx.x < NSB) cur8[threadIdx.x] = histM8[threadIdx.x * NB1 + blk];
    __syncthreads();
    const int q0 = blk * qpb;
    const int q1 = min(q0 + qpb, nquads);
    const float we = w_edge[0], be = b_edge[0];
    const v4i* s4 = (const v4i*)src;
    const v4i* d4 = (const v4i*)dst;
    const v4f* e4 = (const v4f*)ea;
    for (int q = q0 + threadIdx.x; q < q1; q += P1_THR) {
        v4i s = __builtin_nontemporal_load(s4 + q);
        v4i d = __builtin_nontemporal_load(d4 + q);
        v4f e = __builtin_nontemporal_load(e4 + q);
        #pragma unroll
        for (int k = 0; k < 4; ++k) {
            int sv = (k == 0) ? s.x : (k == 1) ? s.y : (k == 2) ? s.z : s.w;
            int dv = (k == 0) ? d.x : (k == 1) ? d.y : (k == 2) ? d.z : d.w;
            float ev = (k == 0) ? e.x : (k == 1) ? e.y : (k == 2) ? e.z : e.w;
            int sb = sv / sbsz;
            int sl = sv - sb * sbsz;
            unsigned short tb = f2h(fmaf(ev, we, be));
            int p = atomicAdd(&cur8[sb], 1);       // LDS-only
            v2u r;
            r.x = ((unsigned)(sl & 0xFFFF) << 16) | (unsigned)tb;
            r.y = (unsigned)dv | ((unsigned)(sl >> 16) << 23);
            recs[p] = r;
        }
    }
}

// ---------------------------------------------------------------------------
// P2: GLOBAL chunking; per-record super resolved against sseg. XCD swizzle.
// LDS counting sort -> fixed slot pairs[(size_t)j*CH] + u16 offset table.
// ZERO global atomics.
// ---------------------------------------------------------------------------
__global__ __launch_bounds__(P2_THR) void k_p2(
    const v2u* __restrict__ recs, const float* __restrict__ x,
    const int* __restrict__ sseg, int sbsz, int DB, int NCH, int bpx, int E,
    unsigned short* __restrict__ ofsT, unsigned* __restrict__ pairs)
{
    __shared__ __align__(16) unsigned pairbuf[CH];  // 32768 B
    __shared__ int hD[DBMAX];
    __shared__ int lofs[DBMAX];
    __shared__ int lcur[DBMAX];
    __shared__ int sS[NSB + 1];

    const int jraw = blockIdx.x;
    const int j = (jraw & 7) * bpx + (jraw >> 3);   // XCD-affine, bijective
    if (j >= NCH) return;
    const int start = j * CH;
    const int n = min(CH, E - start);
    const int tid = threadIdx.x;
    const int wid = tid >> 6, lane = tid & 63;

    if (tid < NSB + 1) sS[tid] = sseg[tid];
    for (int i = tid; i < DBMAX; i += P2_THR) hD[i] = 0;
    __syncthreads();

    // pass A: histogram, 8-deep batches
    #pragma unroll
    for (int half = 0; half < CH / (8 * P2_THR); ++half) {
        unsigned bk[8];
        #pragma unroll
        for (int k = 0; k < 8; ++k) {
            int idx = tid + (half * 8 + k) * P2_THR;
            bk[k] = (idx < n) ? ((recs[start + idx].y & 0x7FFFFFu) >> SHIFT)
                              : 0xFFFFu;
        }
        #pragma unroll
        for (int k = 0; k < 8; ++k)
            if (bk[k] != 0xFFFFu) atomicAdd(&hD[bk[k]], 1);
    }
    __syncthreads();

    // wave 0: exclusive scan of hD -> lofs (5 elems/lane)
    if (wid == 0) {
        const int base = lane * (DBMAX / 64);
        int vals[DBMAX / 64];
        int s = 0;
        #pragma unroll
        for (int k = 0; k < DBMAX / 64; ++k) { vals[k] = s; s += hD[base + k]; }
        int excl = s;
        #pragma unroll
        for (int d = 1; d < 64; d <<= 1) {
            int t = __shfl_up(excl, d, 64);
            if (lane >= d) excl += t;
        }
        excl -= s;
        #pragma unroll
        for (int k = 0; k < DBMAX / 64; ++k) lofs[base + k] = vals[k] + excl;
    }
    __syncthreads();

    // offset table write + local cursors
    const size_t tbase = (size_t)j * (DBMAX + 1);
    for (int b = tid; b < DB; b += P2_THR) {
        lcur[b] = lofs[b];
        ofsT[tbase + b] = (unsigned short)lofs[b];
    }
    if (tid == 0) ofsT[tbase + DB] = (unsigned short)n;
    __syncthreads();

    // pass B: 8-deep batched load + gather (x slice L2-hot), LDS scatter-sort
    #pragma unroll
    for (int half = 0; half < CH / (8 * P2_THR); ++half) {
        v2u r[8];
        #pragma unroll
        for (int k = 0; k < 8; ++k) {
            int idx = tid + (half * 8 + k) * P2_THR;
            if (idx < n) r[k] = recs[start + idx];
            else { r[k].x = 0u; r[k].y = 0u; }
        }
        float xv[8];
        #pragma unroll
        for (int k = 0; k < 8; ++k) {
            int idx = tid + (half * 8 + k) * P2_THR;
            int gp = start + min(idx, n - 1);
            int sbr = 0;
            #pragma unroll
            for (int s = 1; s < NSB; ++s) sbr += (gp >= sS[s]);
            int sl = (int)(r[k].x >> 16) | (int)((r[k].y >> 23) << 16);
            xv[k] = x[(size_t)sbr * sbsz + sl];
        }
        #pragma unroll
        for (int k = 0; k < 8; ++k) {
            int idx = tid + (half * 8 + k) * P2_THR;
            if (idx < n) {
                unsigned d = r[k].y & 0x7FFFFFu;
                float m = xv[k] * h2f((unsigned short)(r[k].x & 0xFFFFu));
                int li = atomicAdd(&lcur[d >> SHIFT], 1);
                pairbuf[li] = ((d & (SLICE - 1)) << 16) | (unsigned)f2h(m);
            }
        }
    }
    __syncthreads();

    // pass C: fully-coalesced uint4 dump into the chunk's fixed slot
    const size_t pbase = (size_t)j * CH;
    uint4* out4 = reinterpret_cast<uint4*>(pairs + pbase);
    const uint4* pb4 = reinterpret_cast<const uint4*>(pairbuf);
    #pragma unroll
    for (int i = 0; i < CH / 4 / P2_THR; ++i)
        out4[tid + i * P2_THR] = pb4[tid + i * P2_THR];
}

// ---------------------------------------------------------------------------
// binB v4 @ SHIFT14: per-bucket block (DB=304), 64KB slice; stage (o0,len)
// per chunk in LDS; each wave processes 8 chunks/iter: 8 independent
// predicated 64-lane pairs loads (avg run 27 -> 42% lane util), then 8
// predicated LDS atomics. Tail loop covers runs > 64.
// ---------------------------------------------------------------------------
__global__ __launch_bounds__(BB_THR) void k_binB(
    const unsigned* __restrict__ pairs,
    const unsigned short* __restrict__ ofsT,
    int NCH, int DB,
    const float* __restrict__ x,
    const float* __restrict__ w_root, const float* __restrict__ b_conv,
    float* __restrict__ nodes, int N)
{
    __shared__ float slice[SLICE];               // 65536 B
    __shared__ unsigned short so0[BB_PH];        // 2048 B
    __shared__ unsigned short sln[BB_PH];        // 2048 B
    const int b = blockIdx.x;
    const int tid = threadIdx.x;
    const int wid = tid >> 6, lane = tid & 63;

    for (int i = tid; i < SLICE; i += BB_THR) slice[i] = 0.0f;
    __syncthreads();

    for (int ch0 = 0; ch0 < NCH; ch0 += BB_PH) {
        const int nc = min(BB_PH, NCH - ch0);
        // stage run bounds (parallel, independent loads)
        for (int c = tid; c < nc; c += BB_THR) {
            const size_t tb = (size_t)(ch0 + c) * (DBMAX + 1);
            int o0 = ofsT[tb + b];
            int o1 = ofsT[tb + b + 1];
            so0[c] = (unsigned short)o0;
            sln[c] = (unsigned short)(o1 - o0);
        }
        __syncthreads();
        // wave-per-8-chunks: 8 independent loads in flight per wave
        for (int c0 = wid * 8; c0 < nc; c0 += BB_NW * 8) {
            int o0r[8], lnr[8];
            #pragma unroll
            for (int k = 0; k < 8; ++k) {
                int c = c0 + k;
                bool v = c < nc;
                o0r[k] = v ? (int)so0[c] : 0;
                lnr[k] = v ? (int)sln[c] : 0;
            }
            unsigned pr[8];
            #pragma unroll
            for (int k = 0; k < 8; ++k) {
                if (lane < lnr[k])
                    pr[k] = pairs[(size_t)(ch0 + c0 + k) * CH + o0r[k] + lane];
            }
            #pragma unroll
            for (int k = 0; k < 8; ++k) {
                if (lane < lnr[k])
                    atomicAdd(&slice[pr[k] >> 16],
                              h2f((unsigned short)(pr[k] & 0xFFFFu)));
            }
            // tail: runs longer than 64
            #pragma unroll
            for (int k = 0; k < 8; ++k) {
                for (int j2 = lane + 64; j2 < lnr[k]; j2 += 64) {
                    unsigned p = pairs[(size_t)(ch0 + c0 + k) * CH + o0r[k] + j2];
                    atomicAdd(&slice[p >> 16],
                              h2f((unsigned short)(p & 0xFFFFu)));
                }
            }
        }
        __syncthreads();
    }

    const float wr = w_root[0], bc = b_conv[0];
    const int gbase = b << SHIFT;
    for (int i = tid; i < SLICE; i += BB_THR) {
        int gi = gbase + i;
        if (gi < N) nodes[gi] = slice[i] + fmaf(__builtin_nontemporal_load(x + gi), wr, bc);
    }
}

// ---------------------------------------------------------------------------
// Mid-fallback: dst-binning with gather (reservation-based) + linear binB
// ---------------------------------------------------------------------------
__global__ __launch_bounds__(512) void k_count_mid(
    const int* __restrict__ dst, int nquads, int qpb, int DB,
    int* __restrict__ gcntD)
{
    __shared__ int hD[DBMAX];
    for (int i = threadIdx.x; i < DB; i += 512) hD[i] = 0;
    __syncthreads();
    const int q0 = blockIdx.x * qpb;
    const int q1 = min(q0 + qpb, nquads);
    const v4i* d4 = (const v4i*)dst;
    for (int q = q0 + threadIdx.x; q < q1; q += 512) {
        v4i d = __builtin_nontemporal_load(d4 + q);
        atomicAdd(&hD[d.x >> SHIFT], 1);
        atomicAdd(&hD[d.y >> SHIFT], 1);
        atomicAdd(&hD[d.z >> SHIFT], 1);
        atomicAdd(&hD[d.w >> SHIFT], 1);
    }
    __syncthreads();
    for (int i = threadIdx.x; i < DB; i += 512)
        if (hD[i]) atomicAdd(&gcntD[i], hD[i]);
}

__global__ void k_scanD(const int* __restrict__ gcntD, int DB,
                        int* __restrict__ bbaseD, int* __restrict__ gcurD)
{
    if (threadIdx.x == 0 && blockIdx.x == 0) {
        int run = 0;
        for (int i = 0; i < DB; ++i) { bbaseD[i] = run; gcurD[i] = run; run += gcntD[i]; }
        bbaseD[DB] = run;
    }
}

__global__ __launch_bounds__(512) void k_binA_resv(
    const float* __restrict__ x,
    const int* __restrict__ src, const int* __restrict__ dst,
    const float* __restrict__ ea,
    const float* __restrict__ w_edge, const float* __restrict__ b_edge,
    int nquads, int qpb, int DB,
    int* __restrict__ gcurD, unsigned* __restrict__ pairs)
{
    __shared__ int hD[DBMAX];
    __shared__ int cur[DBMAX];
    const int q0 = blockIdx.x * qpb;
    const int q1 = min(q0 + qpb, nquads);
    for (int i = threadIdx.x; i < DB; i += 512) hD[i] = 0;
    __syncthreads();
    const v4i* s4 = (const v4i*)src;
    const v4i* d4 = (const v4i*)dst;
    const v4f* e4 = (const v4f*)ea;
    for (int q = q0 + threadIdx.x; q < q1; q += 512) {
        v4i d = d4[q];
        atomicAdd(&hD[d.x >> SHIFT], 1);
        atomicAdd(&hD[d.y >> SHIFT], 1);
        atomicAdd(&hD[d.z >> SHIFT], 1);
        atomicAdd(&hD[d.w >> SHIFT], 1);
    }
    __syncthreads();
    for (int i = threadIdx.x; i < DB; i += 512) {
        int cnt = hD[i];
        cur[i] = cnt ? atomicAdd(&gcurD[i], cnt) : 0;
    }
    __syncthreads();
    const float we = w_edge[0], be = b_edge[0];
    for (int q = q0 + threadIdx.x; q < q1; q += 512) {
        v4i s = __builtin_nontemporal_load(s4 + q);
        v4i d = d4[q];
        v4f e = __builtin_nontemporal_load(e4 + q);
        #pragma unroll
        for (int k = 0; k < 4; ++k) {
            int sv = (k == 0) ? s.x : (k == 1) ? s.y : (k == 2) ? s.z : s.w;
            unsigned dv = (unsigned)((k == 0) ? d.x : (k == 1) ? d.y : (k == 2) ? d.z : d.w);
            float ev = (k == 0) ? e.x : (k == 1) ? e.y : (k == 2) ? e.z : e.w;
            float m = x[sv] * fmaf(ev, we, be);
            int p = atomicAdd(&cur[dv >> SHIFT], 1);
            pairs[p] = ((dv & (SLICE - 1)) << 16) | (unsigned)f2h(m);
        }
    }
}

__global__ __launch_bounds__(1024) void k_binB_lin(
    const unsigned* __restrict__ pairs,
    const int* __restrict__ bbaseD,
    const float* __restrict__ x,
    const float* __restrict__ w_root, const float* __restrict__ b_conv,
    float* __restrict__ nodes, int N)
{
    __shared__ float slice[SLICE];
    const int b = blockIdx.x;
    for (int i = threadIdx.x; i < SLICE; i += 1024) slice[i] = 0.0f;
    __syncthreads();
    const int p0 = bbaseD[b];
    const int p1 = bbaseD[b + 1];
    for (int i = p0 + threadIdx.x; i < p1; i += 1024) {
        unsigned p = __builtin_nontemporal_load(pairs + i);
        atomicAdd(&slice[p >> 16], h2f((unsigned short)(p & 0xFFFFu)));
    }
    __syncthreads();
    const float wr = w_root[0], bc = b_conv[0];
    const int gbase = b << SHIFT;
    for (int i = threadIdx.x; i < SLICE; i += 1024) {
        int gi = gbase + i;
        if (gi < N) nodes[gi] = slice[i] + fmaf(__builtin_nontemporal_load(x + gi), wr, bc);
    }
}

// ---------------------------------------------------------------------------
// Bottom fallback: global atomics
// ---------------------------------------------------------------------------
__global__ __launch_bounds__(256) void edge_kernel_atomic(
    const float* __restrict__ x,
    const int*   __restrict__ src, const int* __restrict__ dst,
    const float* __restrict__ ea,
    const float* __restrict__ w_edge, const float* __restrict__ b_edge,
    float* __restrict__ agg, int E)
{
    const float we = w_edge[0], be = b_edge[0];
    int tid = blockIdx.x * blockDim.x + threadIdx.x;
    int stride = gridDim.x * blockDim.x;
    for (int i = tid; i < E; i += stride)
        atomicAdd(&agg[dst[i]], x[src[i]] * fmaf(ea[i], we, be));
}

__global__ __launch_bounds__(256) void finalize_nodes(
    const float* __restrict__ x, const float* __restrict__ agg,
    const float* __restrict__ w_root, const float* __restrict__ b_conv,
    float* __restrict__ nodes, int N)
{
    const float wr = w_root[0], bc = b_conv[0];
    int i = blockIdx.x * blockDim.x + threadIdx.x;
    int stride = gridDim.x * blockDim.x;
    for (; i < N; i += stride) nodes[i] = agg[i] + fmaf(x[i], wr, bc);
}

// ---------------------------------------------------------------------------
// Head MLP over per-graph node vectors + softmax
// ---------------------------------------------------------------------------
__global__ __launch_bounds__(HEAD_BLK) void head_kernel(
    const float* __restrict__ nodes,
    const float* __restrict__ W1, const float* __restrict__ b1,
    const float* __restrict__ W2, const float* __restrict__ b2,
    const float* __restrict__ W3, const float* __restrict__ b3,
    float* __restrict__ out, int G)
{
    __shared__ float s_nodes[HEAD_BLK * NPG];   // 38912 B
    __shared__ float s_W1[NPG * 4];
    __shared__ float s_W2[4 * 4];
    __shared__ float s_W3[4 * 12];
    __shared__ float s_b1[4];
    __shared__ float s_b2[4];
    __shared__ float s_b3[12];

    const int tid = threadIdx.x;
    if (tid < NPG * 4) s_W1[tid] = W1[tid];
    if (tid >= 160 && tid < 176) s_W2[tid - 160] = W2[tid - 160];
    if (tid >= 176 && tid < 224) s_W3[tid - 176] = W3[tid - 176];
    if (tid >= 224 && tid < 228) s_b1[tid - 224] = b1[tid - 224];
    if (tid >= 228 && tid < 232) s_b2[tid - 228] = b2[tid - 228];
    if (tid >= 232 && tid < 244) s_b3[tid - 232] = b3[tid - 232];

    const int g0 = blockIdx.x * HEAD_BLK;
    const size_t ebase = (size_t)g0 * NPG;
    const int nelem = HEAD_BLK * NPG;
    const int avail = min(nelem, (G - g0) * NPG);
    for (int i = tid; i < avail; i += HEAD_BLK) s_nodes[i] = nodes[ebase + i];
    __syncthreads();

    const int g = g0 + tid;
    if (g >= G) return;
    const float* nd = &s_nodes[tid * NPG];

    float h1[4];
    #pragma unroll
    for (int k = 0; k < 4; ++k) h1[k] = s_b1[k];
    #pragma unroll
    for (int j = 0; j < NPG; ++j) {
        const float nj = nd[j];
        #pragma unroll
        for (int k = 0; k < 4; ++k) h1[k] = fmaf(nj, s_W1[j * 4 + k], h1[k]);
    }
    #pragma unroll
    for (int k = 0; k < 4; ++k) h1[k] = h1[k] >= 0.0f ? h1[k] : 0.01f * h1[k];

    float h2[4];
    #pragma unroll
    for (int k = 0; k < 4; ++k) {
        float a = s_b2[k];
        #pragma unroll
        for (int j = 0; j < 4; ++j) a = fmaf(h1[j], s_W2[j * 4 + k], a);
        h2[k] = a >= 0.0f ? a : 0.01f * a;
    }

    float h3[12];
    #pragma unroll
    for (int k = 0; k < 12; ++k) {
        float a = s_b3[k];
        #pragma unroll
        for (int j = 0; j < 4; ++j) a = fmaf(h2[j], s_W3[j * 12 + k], a);
        h3[k] = a >= 0.0f ? a : 0.01f * a;
    }

    float m = h3[0];
    #pragma unroll
    for (int k = 1; k < 12; ++k) m = fmaxf(m, h3[k]);
    float sum = 0.0f;
    #pragma unroll
    for (int k = 0; k < 12; ++k) { h3[k] = expf(h3[k] - m); sum += h3[k]; }
    const float inv = 1.0f / sum;

    float4* o = reinterpret_cast<float4*>(out + (size_t)g * 12);
    o[0] = make_float4(h3[0] * inv, h3[1] * inv, h3[2]  * inv, h3[3]  * inv);
    o[1] = make_float4(h3[4] * inv, h3[5] * inv, h3[6]  * inv, h3[7]  * inv);
    o[2] = make_float4(h3[8] * inv, h3[9] * inv, h3[10] * inv, h3[11] * inv);
}

extern "C" void kernel_launch(void* const* d_in, const int* in_sizes, int n_in,
                              void* d_out, int out_size, void* d_ws, size_t ws_size,
                              hipStream_t stream)
{
    const float* x      = (const float*)d_in[0];
    const int*   eidx   = (const int*)  d_in[1];
    const float* ea     = (const float*)d_in[2];
    const float* w_edge = (const float*)d_in[3];
    const float* b_edge = (const float*)d_in[4];
    const float* w_root = (const float*)d_in[5];
    const float* b_conv = (const float*)d_in[6];
    const float* W1 = (const float*)d_in[7];
    const float* b1 = (const float*)d_in[8];
    const float* W2 = (const float*)d_in[9];
    const float* b2 = (const float*)d_in[10];
    const float* W3 = (const float*)d_in[11];
    const float* b3 = (const float*)d_in[12];
    float* out = (float*)d_out;

    const int N = in_sizes[0];
    const int E = in_sizes[2];
    const int G = N / NPG;
    const int* src = eidx;
    const int* dst = eidx + E;
    const int nquads = E / 4;
    const int DB = (N + SLICE - 1) >> SHIFT;

    const int hblocks = (G + HEAD_BLK - 1) / HEAD_BLK;
    char* ws = (char*)d_ws;

    const bool quadok = (E % 4) == 0 && DB <= DBMAX && DB >= 1;
    const int  sbsz   = (N % NSB == 0) ? (N / NSB) : 0;

    const int NCH = (E + CH - 1) / CH;            // global chunk count
    const int bpx = (NCH + 7) / 8;

    // meta ints: histM8[NSB*NB1] | sseg[NSB+1] | gcntD[DBMAX] | gcurD[DBMAX] |
    //            bbaseD[DBMAX+1]
    const size_t META_INTS = (size_t)NSB * NB1 + (NSB + 1) + DBMAX + DBMAX + (DBMAX + 1);

    // v5 layout: recs (E*8) | pairs (NCH*CH*4) | ofsT (NCH*(DBMAX+1)*2) |
    //            nodes (N*4) | meta
    size_t off_pairs = (size_t)E * 8;
    size_t sz_pairs  = (size_t)NCH * CH * 4;
    size_t off_ofsT  = off_pairs + sz_pairs;
    size_t sz_ofsT   = ((size_t)NCH * (DBMAX + 1) * 2 + 15) & ~(size_t)15;
    size_t off_nodes = off_ofsT + sz_ofsT;
    size_t off_meta  = off_nodes + (size_t)N * 4;
    size_t need_v5   = off_meta + META_INTS * 4;

    // mid layout: pairs (E*4) | nodes | meta
    size_t off_nodes_mid = (size_t)E * 4;
    size_t off_meta_mid  = off_nodes_mid + (size_t)N * 4;
    size_t need_mid      = off_meta_mid + META_INTS * 4;

    if (quadok && sbsz > 0 && need_v5 <= ws_size) {
        v2u*            recs  = (v2u*)ws;
        unsigned*       pairs = (unsigned*)(ws + off_pairs);
        unsigned short* ofsT  = (unsigned short*)(ws + off_ofsT);
        float*          nodes = (float*)(ws + off_nodes);
        int*            meta  = (int*)(ws + off_meta);
        int* histM8 = meta;
        int* sseg   = meta + NSB * NB1;

        const int qpb = (nquads + NB1 - 1) / NB1;
        k_p1a<<<NB1, P1_THR, 0, stream>>>(src, nquads, qpb, sbsz, histM8);
        k_scanM<<<1, 512, 0, stream>>>(histM8, sseg);
        k_p1b<<<NB1, P1_THR, 0, stream>>>(src, dst, ea, w_edge, b_edge,
                                          nquads, qpb, sbsz, histM8, recs);
        k_p2<<<8 * bpx, P2_THR, 0, stream>>>(recs, x, sseg, sbsz, DB, NCH, bpx,
                                             E, ofsT, pairs);
        k_binB<<<DB, BB_THR, 0, stream>>>(pairs, ofsT, NCH, DB, x,
                                          w_root, b_conv, nodes, N);
        head_kernel<<<hblocks, HEAD_BLK, 0, stream>>>(nodes, W1, b1, W2, b2,
                                                      W3, b3, out, G);
    } else if (quadok && need_mid <= ws_size) {
        unsigned* pairs = (unsigned*)ws;
        float*    nodes = (float*)(ws + off_nodes_mid);
        int*      meta  = (int*)(ws + off_meta_mid);
        int* gcntD  = meta + NSB * NB1 + (NSB + 1);
        int* gcurD  = gcntD + DBMAX;
        int* bbaseD = gcurD + DBMAX;

        hipMemsetAsync(gcntD, 0, DBMAX * sizeof(int), stream);
        const int NBm = 2048;
        const int qpbm = (nquads + NBm - 1) / NBm;
        k_count_mid<<<NBm, 512, 0, stream>>>(dst, nquads, qpbm, DB, gcntD);
        k_scanD<<<1, 64, 0, stream>>>(gcntD, DB, bbaseD, gcurD);
        k_binA_resv<<<NBm, 512, 0, stream>>>(x, src, dst, ea, w_edge, b_edge,
                                             nquads, qpbm, DB, gcurD, pairs);
        k_binB_lin<<<DB, 1024, 0, stream>>>(pairs, bbaseD, x, w_root, b_conv,
                                            nodes, N);
        head_kernel<<<hblocks, HEAD_BLK, 0, stream>>>(nodes, W1, b1, W2, b2,
                                                      W3, b3, out, G);
    } else {
        float* agg   = (float*)d_ws;
        float* nodes = agg + N;
        hipMemsetAsync(agg, 0, (size_t)N * sizeof(float), stream);
        edge_kernel_atomic<<<2048, 256, 0, stream>>>(x, src, dst, ea, w_edge,
                                                     b_edge, agg, E);
        finalize_nodes<<<2048, 256, 0, stream>>>(x, agg, w_root, b_conv, nodes, N);
        head_kernel<<<hblocks, HEAD_BLK, 0, stream>>>(nodes, W1, b1, W2, b2,
                                                      W3, b3, out, G);
    }
}

// Round 18
// 940.262 us; speedup vs baseline: 1.2948x; 1.2332x over previous
//
#include <hip/hip_runtime.h>
#include <hip/hip_fp16.h>

#define NPG 38
#define HEAD_BLK 256
#define SZMAX 19456               // max nodes per dst-bucket (76KB LDS slice)
#define DBMAX 320                 // max dst buckets
#define NSB 8                     // src super-buckets
#define NB1 1024                  // blocks for P1a/P1b
#define P1_THR 512
#define CH 8192                   // records per P2 chunk
#define P2_THR 512
#define BB_THR 1024
#define BB_NW (BB_THR / 64)       // 16 waves
#define BB_PH 1024                // chunks staged per binB phase

typedef int      v4i __attribute__((ext_vector_type(4)));
typedef float    v4f __attribute__((ext_vector_type(4)));
typedef unsigned v2u __attribute__((ext_vector_type(2)));

static inline __device__ unsigned short f2h(float f) {
    return __half_as_ushort(__float2half(f));
}
static inline __device__ float h2f(unsigned short b) {
    return __half2float(__ushort_as_half(b));
}
// exact floor(v / S) for v < 2^23 via 40-bit magic (M = 2^40/S + 1)
static inline __device__ int divS(unsigned v, unsigned long long M) {
    return (int)(((unsigned long long)v * M) >> 40);
}

// ---------------------------------------------------------------------------
// P1a: per-block per-super counts only (src read only; plain stores).
// ---------------------------------------------------------------------------
__global__ __launch_bounds__(P1_THR) void k_p1a(
    const int* __restrict__ src, int nquads, int qpb, int sbsz,
    int* __restrict__ histM8)          // [NSB][NB1]
{
    __shared__ int h8[NSB];
    const int tid = threadIdx.x;
    if (tid < NSB) h8[tid] = 0;
    __syncthreads();
    const int blk = blockIdx.x;
    const int q0 = blk * qpb;
    const int q1 = min(q0 + qpb, nquads);
    const v4i* s4 = (const v4i*)src;
    for (int q = q0 + tid; q < q1; q += P1_THR) {
        v4i s = __builtin_nontemporal_load(s4 + q);
        atomicAdd(&h8[s.x / sbsz], 1);
        atomicAdd(&h8[s.y / sbsz], 1);
        atomicAdd(&h8[s.z / sbsz], 1);
        atomicAdd(&h8[s.w / sbsz], 1);
    }
    __syncthreads();
    if (tid < NSB) histM8[tid * NB1 + blk] = h8[tid];
}

// ---------------------------------------------------------------------------
// scanM: histM8 -> absolute per-(super,block) emit offsets (in place) + sseg.
// ---------------------------------------------------------------------------
__global__ __launch_bounds__(512) void k_scanM(
    int* __restrict__ histM8, int* __restrict__ sseg)
{
    __shared__ int stot[NSB];
    __shared__ int sbase[NSB + 1];
    const int tid = threadIdx.x;
    const int wid = tid >> 6, lane = tid & 63;

    const int base = wid * NB1 + lane * (NB1 / 64);
    int vals[NB1 / 64];
    int s = 0;
    #pragma unroll
    for (int k = 0; k < NB1 / 64; ++k) { vals[k] = s; s += histM8[base + k]; }
    int excl = s;
    #pragma unroll
    for (int d = 1; d < 64; d <<= 1) {
        int t = __shfl_up(excl, d, 64);
        if (lane >= d) excl += t;
    }
    excl -= s;
    if (lane == 63) stot[wid] = excl + s;
    __syncthreads();
    if (tid == 0) {
        int run = 0;
        for (int i = 0; i < NSB; ++i) { sbase[i] = run; run += stot[i]; }
        sbase[NSB] = run;
    }
    __syncthreads();
    const int b0 = sbase[wid] + excl;
    #pragma unroll
    for (int k = 0; k < NB1 / 64; ++k) histM8[base + k] = vals[k] + b0;
    if (tid < NSB + 1) sseg[tid] = sbase[tid];
}

// ---------------------------------------------------------------------------
// P1b: re-read edges, emit records at precomputed absolute offsets.
// Record = 8B: lo = (src_local[15:0]<<16)|fp16(theta), hi = dst|(sl>>16)<<23
// ---------------------------------------------------------------------------
__global__ __launch_bounds__(P1_THR) void k_p1b(
    const int* __restrict__ src, const int* __restrict__ dst,
    const float* __restrict__ ea,
    const float* __restrict__ w_edge, const float* __restrict__ b_edge,
    int nquads, int qpb, int sbsz,
    const int* __restrict__ histM8,
    v2u* __restrict__ recs)
{
    __shared__ int cur8[NSB];
    const int blk = blockIdx.x;
    if (threadIdx.x < NSB) cur8[threadIdx.x] = histM8[threadIdx.x * NB1 + blk];
    __syncthreads();
    const int q0 = blk * qpb;
    const int q1 = min(q0 + qpb, nquads);
    const float we = w_edge[0], be = b_edge[0];
    const v4i* s4 = (const v4i*)src;
    const v4i* d4 = (const v4i*)dst;
    const v4f* e4 = (const v4f*)ea;
    for (int q = q0 + threadIdx.x; q < q1; q += P1_THR) {
        v4i s = __builtin_nontemporal_load(s4 + q);
        v4i d = __builtin_nontemporal_load(d4 + q);
        v4f e = __builtin_nontemporal_load(e4 + q);
        #pragma unroll
        for (int k = 0; k < 4; ++k) {
            int sv = (k == 0) ? s.x : (k == 1) ? s.y : (k == 2) ? s.z : s.w;
            int dv = (k == 0) ? d.x : (k == 1) ? d.y : (k == 2) ? d.z : d.w;
            float ev = (k == 0) ? e.x : (k == 1) ? e.y : (k == 2) ? e.z : e.w;
            int sb = sv / sbsz;
            int sl = sv - sb * sbsz;
            unsigned short tb = f2h(fmaf(ev, we, be));
            int p = atomicAdd(&cur8[sb], 1);       // LDS-only
            v2u r;
            r.x = ((unsigned)(sl & 0xFFFF) << 16) | (unsigned)tb;
            r.y = (unsigned)dv | ((unsigned)(sl >> 16) << 23);
            recs[p] = r;
        }
    }
}

// ---------------------------------------------------------------------------
// P2: GLOBAL chunking; bucket = dst / SZ via magic division (DB=256).
// LDS counting sort -> fixed slot pairs[(size_t)j*CH] + u16 offset table.
// ZERO global atomics.
// ---------------------------------------------------------------------------
__global__ __launch_bounds__(P2_THR) void k_p2(
    const v2u* __restrict__ recs, const float* __restrict__ x,
    const int* __restrict__ sseg, int sbsz, int DB, int NCH, int bpx, int E,
    unsigned SZ, unsigned long long MAGIC,
    unsigned short* __restrict__ ofsT, unsigned* __restrict__ pairs)
{
    __shared__ __align__(16) unsigned pairbuf[CH];  // 32768 B
    __shared__ int hD[DBMAX];
    __shared__ int lofs[DBMAX];
    __shared__ int lcur[DBMAX];
    __shared__ int sS[NSB + 1];

    const int jraw = blockIdx.x;
    const int j = (jraw & 7) * bpx + (jraw >> 3);   // XCD-affine, bijective
    if (j >= NCH) return;
    const int start = j * CH;
    const int n = min(CH, E - start);
    const int tid = threadIdx.x;
    const int wid = tid >> 6, lane = tid & 63;

    if (tid < NSB + 1) sS[tid] = sseg[tid];
    for (int i = tid; i < DBMAX; i += P2_THR) hD[i] = 0;
    __syncthreads();

    // pass A: histogram, 8-deep batches
    #pragma unroll
    for (int half = 0; half < CH / (8 * P2_THR); ++half) {
        int bk[8];
        #pragma unroll
        for (int k = 0; k < 8; ++k) {
            int idx = tid + (half * 8 + k) * P2_THR;
            bk[k] = (idx < n)
                  ? divS(recs[start + idx].y & 0x7FFFFFu, MAGIC) : -1;
        }
        #pragma unroll
        for (int k = 0; k < 8; ++k)
            if (bk[k] >= 0) atomicAdd(&hD[bk[k]], 1);
    }
    __syncthreads();

    // wave 0: exclusive scan of hD -> lofs (5 elems/lane)
    if (wid == 0) {
        const int base = lane * (DBMAX / 64);
        int vals[DBMAX / 64];
        int s = 0;
        #pragma unroll
        for (int k = 0; k < DBMAX / 64; ++k) { vals[k] = s; s += hD[base + k]; }
        int excl = s;
        #pragma unroll
        for (int d = 1; d < 64; d <<= 1) {
            int t = __shfl_up(excl, d, 64);
            if (lane >= d) excl += t;
        }
        excl -= s;
        #pragma unroll
        for (int k = 0; k < DBMAX / 64; ++k) lofs[base + k] = vals[k] + excl;
    }
    __syncthreads();

    // offset table write + local cursors
    const size_t tbase = (size_t)j * (DBMAX + 1);
    for (int b = tid; b < DB; b += P2_THR) {
        lcur[b] = lofs[b];
        ofsT[tbase + b] = (unsigned short)lofs[b];
    }
    if (tid == 0) ofsT[tbase + DB] = (unsigned short)n;
    __syncthreads();

    // pass B: 8-deep batched load + gather (x slice L2-hot), LDS scatter-sort
    #pragma unroll
    for (int half = 0; half < CH / (8 * P2_THR); ++half) {
        v2u r[8];
        #pragma unroll
        for (int k = 0; k < 8; ++k) {
            int idx = tid + (half * 8 + k) * P2_THR;
            if (idx < n) r[k] = recs[start + idx];
            else { r[k].x = 0u; r[k].y = 0u; }
        }
        float xv[8];
        #pragma unroll
        for (int k = 0; k < 8; ++k) {
            int idx = tid + (half * 8 + k) * P2_THR;
            int gp = start + min(idx, n - 1);
            int sbr = 0;
            #pragma unroll
            for (int s = 1; s < NSB; ++s) sbr += (gp >= sS[s]);
            int sl = (int)(r[k].x >> 16) | (int)((r[k].y >> 23) << 16);
            xv[k] = x[(size_t)sbr * sbsz + sl];
        }
        #pragma unroll
        for (int k = 0; k < 8; ++k) {
            int idx = tid + (half * 8 + k) * P2_THR;
            if (idx < n) {
                unsigned d = r[k].y & 0x7FFFFFu;
                int bb = divS(d, MAGIC);
                unsigned dl = d - (unsigned)bb * SZ;
                float m = xv[k] * h2f((unsigned short)(r[k].x & 0xFFFFu));
                int li = atomicAdd(&lcur[bb], 1);
                pairbuf[li] = (dl << 16) | (unsigned)f2h(m);
            }
        }
    }
    __syncthreads();

    // pass C: fully-coalesced uint4 dump into the chunk's fixed slot
    const size_t pbase = (size_t)j * CH;
    uint4* out4 = reinterpret_cast<uint4*>(pairs + pbase);
    const uint4* pb4 = reinterpret_cast<const uint4*>(pairbuf);
    #pragma unroll
    for (int i = 0; i < CH / 4 / P2_THR; ++i)
        out4[tid + i * P2_THR] = pb4[tid + i * P2_THR];
}

// ---------------------------------------------------------------------------
// binB @ DB=256: one bucket per CU (zero tail imbalance), 76KB slice; stage
// (o0,len) per chunk in LDS; each wave processes 8 chunks/iter: 8 independent
// predicated 64-lane pairs loads (avg run 32 -> 50% lane util), then 8
// predicated LDS atomics. Tail loop covers runs > 64.
// ---------------------------------------------------------------------------
__global__ __launch_bounds__(BB_THR) void k_binB(
    const unsigned* __restrict__ pairs,
    const unsigned short* __restrict__ ofsT,
    int NCH, int DB, unsigned SZ,
    const float* __restrict__ x,
    const float* __restrict__ w_root, const float* __restrict__ b_conv,
    float* __restrict__ nodes, int N)
{
    __shared__ float slice[SZMAX];               // 77824 B
    __shared__ unsigned short so0[BB_PH];        // 2048 B
    __shared__ unsigned short sln[BB_PH];        // 2048 B
    const int b = blockIdx.x;
    const int tid = threadIdx.x;
    const int wid = tid >> 6, lane = tid & 63;

    for (int i = tid; i < (int)SZ; i += BB_THR) slice[i] = 0.0f;
    __syncthreads();

    for (int ch0 = 0; ch0 < NCH; ch0 += BB_PH) {
        const int nc = min(BB_PH, NCH - ch0);
        // stage run bounds (parallel, independent loads)
        for (int c = tid; c < nc; c += BB_THR) {
            const size_t tb = (size_t)(ch0 + c) * (DBMAX + 1);
            int o0 = ofsT[tb + b];
            int o1 = ofsT[tb + b + 1];
            so0[c] = (unsigned short)o0;
            sln[c] = (unsigned short)(o1 - o0);
        }
        __syncthreads();
        // wave-per-8-chunks: 8 independent loads in flight per wave
        for (int c0 = wid * 8; c0 < nc; c0 += BB_NW * 8) {
            int o0r[8], lnr[8];
            #pragma unroll
            for (int k = 0; k < 8; ++k) {
                int c = c0 + k;
                bool v = c < nc;
                o0r[k] = v ? (int)so0[c] : 0;
                lnr[k] = v ? (int)sln[c] : 0;
            }
            unsigned pr[8];
            #pragma unroll
            for (int k = 0; k < 8; ++k) {
                if (lane < lnr[k])
                    pr[k] = pairs[(size_t)(ch0 + c0 + k) * CH + o0r[k] + lane];
            }
            #pragma unroll
            for (int k = 0; k < 8; ++k) {
                if (lane < lnr[k])
                    atomicAdd(&slice[pr[k] >> 16],
                              h2f((unsigned short)(pr[k] & 0xFFFFu)));
            }
            // tail: runs longer than 64
            #pragma unroll
            for (int k = 0; k < 8; ++k) {
                for (int j2 = lane + 64; j2 < lnr[k]; j2 += 64) {
                    unsigned p = pairs[(size_t)(ch0 + c0 + k) * CH + o0r[k] + j2];
                    atomicAdd(&slice[p >> 16],
                              h2f((unsigned short)(p & 0xFFFFu)));
                }
            }
        }
        __syncthreads();
    }

    const float wr = w_root[0], bc = b_conv[0];
    const int gbase = b * (int)SZ;
    for (int i = tid; i < (int)SZ; i += BB_THR) {
        int gi = gbase + i;
        if (gi < N) nodes[gi] = slice[i] + fmaf(__builtin_nontemporal_load(x + gi), wr, bc);
    }
}

// ---------------------------------------------------------------------------
// Mid-fallback: dst-binning with gather (reservation-based) + linear binB
// ---------------------------------------------------------------------------
__global__ __launch_bounds__(512) void k_count_mid(
    const int* __restrict__ dst, int nquads, int qpb, int DB,
    unsigned long long MAGIC, int* __restrict__ gcntD)
{
    __shared__ int hD[DBMAX];
    for (int i = threadIdx.x; i < DB; i += 512) hD[i] = 0;
    __syncthreads();
    const int q0 = blockIdx.x * qpb;
    const int q1 = min(q0 + qpb, nquads);
    const v4i* d4 = (const v4i*)dst;
    for (int q = q0 + threadIdx.x; q < q1; q += 512) {
        v4i d = __builtin_nontemporal_load(d4 + q);
        atomicAdd(&hD[divS((unsigned)d.x, MAGIC)], 1);
        atomicAdd(&hD[divS((unsigned)d.y, MAGIC)], 1);
        atomicAdd(&hD[divS((unsigned)d.z, MAGIC)], 1);
        atomicAdd(&hD[divS((unsigned)d.w, MAGIC)], 1);
    }
    __syncthreads();
    for (int i = threadIdx.x; i < DB; i += 512)
        if (hD[i]) atomicAdd(&gcntD[i], hD[i]);
}

__global__ void k_scanD(const int* __restrict__ gcntD, int DB,
                        int* __restrict__ bbaseD, int* __restrict__ gcurD)
{
    if (threadIdx.x == 0 && blockIdx.x == 0) {
        int run = 0;
        for (int i = 0; i < DB; ++i) { bbaseD[i] = run; gcurD[i] = run; run += gcntD[i]; }
        bbaseD[DB] = run;
    }
}

__global__ __launch_bounds__(512) void k_binA_resv(
    const float* __restrict__ x,
    const int* __restrict__ src, const int* __restrict__ dst,
    const float* __restrict__ ea,
    const float* __restrict__ w_edge, const float* __restrict__ b_edge,
    int nquads, int qpb, int DB, unsigned SZ, unsigned long long MAGIC,
    int* __restrict__ gcurD, unsigned* __restrict__ pairs)
{
    __shared__ int hD[DBMAX];
    __shared__ int cur[DBMAX];
    const int q0 = blockIdx.x * qpb;
    const int q1 = min(q0 + qpb, nquads);
    for (int i = threadIdx.x; i < DB; i += 512) hD[i] = 0;
    __syncthreads();
    const v4i* s4 = (const v4i*)src;
    const v4i* d4 = (const v4i*)dst;
    const v4f* e4 = (const v4f*)ea;
    for (int q = q0 + threadIdx.x; q < q1; q += 512) {
        v4i d = d4[q];
        atomicAdd(&hD[divS((unsigned)d.x, MAGIC)], 1);
        atomicAdd(&hD[divS((unsigned)d.y, MAGIC)], 1);
        atomicAdd(&hD[divS((unsigned)d.z, MAGIC)], 1);
        atomicAdd(&hD[divS((unsigned)d.w, MAGIC)], 1);
    }
    __syncthreads();
    for (int i = threadIdx.x; i < DB; i += 512) {
        int cnt = hD[i];
        cur[i] = cnt ? atomicAdd(&gcurD[i], cnt) : 0;
    }
    __syncthreads();
    const float we = w_edge[0], be = b_edge[0];
    for (int q = q0 + threadIdx.x; q < q1; q += 512) {
        v4i s = __builtin_nontemporal_load(s4 + q);
        v4i d = d4[q];
        v4f e = __builtin_nontemporal_load(e4 + q);
        #pragma unroll
        for (int k = 0; k < 4; ++k) {
            int sv = (k == 0) ? s.x : (k == 1) ? s.y : (k == 2) ? s.z : s.w;
            unsigned dv = (unsigned)((k == 0) ? d.x : (k == 1) ? d.y : (k == 2) ? d.z : d.w);
            float ev = (k == 0) ? e.x : (k == 1) ? e.y : (k == 2) ? e.z : e.w;
            float m = x[sv] * fmaf(ev, we, be);
            int bb = divS(dv, MAGIC);
            unsigned dl = dv - (unsigned)bb * SZ;
            int p = atomicAdd(&cur[bb], 1);
            pairs[p] = (dl << 16) | (unsigned)f2h(m);
        }
    }
}

__global__ __launch_bounds__(1024) void k_binB_lin(
    const unsigned* __restrict__ pairs,
    const int* __restrict__ bbaseD, unsigned SZ,
    const float* __restrict__ x,
    const float* __restrict__ w_root, const float* __restrict__ b_conv,
    float* __restrict__ nodes, int N)
{
    __shared__ float slice[SZMAX];
    const int b = blockIdx.x;
    for (int i = threadIdx.x; i < (int)SZ; i += 1024) slice[i] = 0.0f;
    __syncthreads();
    const int p0 = bbaseD[b];
    const int p1 = bbaseD[b + 1];
    for (int i = p0 + threadIdx.x; i < p1; i += 1024) {
        unsigned p = __builtin_nontemporal_load(pairs + i);
        atomicAdd(&slice[p >> 16], h2f((unsigned short)(p & 0xFFFFu)));
    }
    __syncthreads();
    const float wr = w_root[0], bc = b_conv[0];
    const int gbase = b * (int)SZ;
    for (int i = threadIdx.x; i < (int)SZ; i += 1024) {
        int gi = gbase + i;
        if (gi < N) nodes[gi] = slice[i] + fmaf(__builtin_nontemporal_load(x + gi), wr, bc);
    }
}

// ---------------------------------------------------------------------------
// Bottom fallback: global atomics
// ---------------------------------------------------------------------------
__global__ __launch_bounds__(256) void edge_kernel_atomic(
    const float* __restrict__ x,
    const int*   __restrict__ src, const int* __restrict__ dst,
    const float* __restrict__ ea,
    const float* __restrict__ w_edge, const float* __restrict__ b_edge,
    float* __restrict__ agg, int E)
{
    const float we = w_edge[0], be = b_edge[0];
    int tid = blockIdx.x * blockDim.x + threadIdx.x;
    int stride = gridDim.x * blockDim.x;
    for (int i = tid; i < E; i += stride)
        atomicAdd(&agg[dst[i]], x[src[i]] * fmaf(ea[i], we, be));
}

__global__ __launch_bounds__(256) void finalize_nodes(
    const float* __restrict__ x, const float* __restrict__ agg,
    const float* __restrict__ w_root, const float* __restrict__ b_conv,
    float* __restrict__ nodes, int N)
{
    const float wr = w_root[0], bc = b_conv[0];
    int i = blockIdx.x * blockDim.x + threadIdx.x;
    int stride = gridDim.x * blockDim.x;
    for (; i < N; i += stride) nodes[i] = agg[i] + fmaf(x[i], wr, bc);
}

// ---------------------------------------------------------------------------
// Head MLP over per-graph node vectors + softmax
// ---------------------------------------------------------------------------
__global__ __launch_bounds__(HEAD_BLK) void head_kernel(
    const float* __restrict__ nodes,
    const float* __restrict__ W1, const float* __restrict__ b1,
    const float* __restrict__ W2, const float* __restrict__ b2,
    const float* __restrict__ W3, const float* __restrict__ b3,
    float* __restrict__ out, int G)
{
    __shared__ float s_nodes[HEAD_BLK * NPG];   // 38912 B
    __shared__ float s_W1[NPG * 4];
    __shared__ float s_W2[4 * 4];
    __shared__ float s_W3[4 * 12];
    __shared__ float s_b1[4];
    __shared__ float s_b2[4];
    __shared__ float s_b3[12];

    const int tid = threadIdx.x;
    if (tid < NPG * 4) s_W1[tid] = W1[tid];
    if (tid >= 160 && tid < 176) s_W2[tid - 160] = W2[tid - 160];
    if (tid >= 176 && tid < 224) s_W3[tid - 176] = W3[tid - 176];
    if (tid >= 224 && tid < 228) s_b1[tid - 224] = b1[tid - 224];
    if (tid >= 228 && tid < 232) s_b2[tid - 228] = b2[tid - 228];
    if (tid >= 232 && tid < 244) s_b3[tid - 232] = b3[tid - 232];

    const int g0 = blockIdx.x * HEAD_BLK;
    const size_t ebase = (size_t)g0 * NPG;
    const int nelem = HEAD_BLK * NPG;
    const int avail = min(nelem, (G - g0) * NPG);
    for (int i = tid; i < avail; i += HEAD_BLK) s_nodes[i] = nodes[ebase + i];
    __syncthreads();

    const int g = g0 + tid;
    if (g >= G) return;
    const float* nd = &s_nodes[tid * NPG];

    float h1[4];
    #pragma unroll
    for (int k = 0; k < 4; ++k) h1[k] = s_b1[k];
    #pragma unroll
    for (int j = 0; j < NPG; ++j) {
        const float nj = nd[j];
        #pragma unroll
        for (int k = 0; k < 4; ++k) h1[k] = fmaf(nj, s_W1[j * 4 + k], h1[k]);
    }
    #pragma unroll
    for (int k = 0; k < 4; ++k) h1[k] = h1[k] >= 0.0f ? h1[k] : 0.01f * h1[k];

    float h2[4];
    #pragma unroll
    for (int k = 0; k < 4; ++k) {
        float a = s_b2[k];
        #pragma unroll
        for (int j = 0; j < 4; ++j) a = fmaf(h1[j], s_W2[j * 4 + k], a);
        h2[k] = a >= 0.0f ? a : 0.01f * a;
    }

    float h3[12];
    #pragma unroll
    for (int k = 0; k < 12; ++k) {
        float a = s_b3[k];
        #pragma unroll
        for (int j = 0; j < 4; ++j) a = fmaf(h2[j], s_W3[j * 12 + k], a);
        h3[k] = a >= 0.0f ? a : 0.01f * a;
    }

    float m = h3[0];
    #pragma unroll
    for (int k = 1; k < 12; ++k) m = fmaxf(m, h3[k]);
    float sum = 0.0f;
    #pragma unroll
    for (int k = 0; k < 12; ++k) { h3[k] = expf(h3[k] - m); sum += h3[k]; }
    const float inv = 1.0f / sum;

    float4* o = reinterpret_cast<float4*>(out + (size_t)g * 12);
    o[0] = make_float4(h3[0] * inv, h3[1] * inv, h3[2]  * inv, h3[3]  * inv);
    o[1] = make_float4(h3[4] * inv, h3[5] * inv, h3[6]  * inv, h3[7]  * inv);
    o[2] = make_float4(h3[8] * inv, h3[9] * inv, h3[10] * inv, h3[11] * inv);
}

extern "C" void kernel_launch(void* const* d_in, const int* in_sizes, int n_in,
                              void* d_out, int out_size, void* d_ws, size_t ws_size,
                              hipStream_t stream)
{
    const float* x      = (const float*)d_in[0];
    const int*   eidx   = (const int*)  d_in[1];
    const float* ea     = (const float*)d_in[2];
    const float* w_edge = (const float*)d_in[3];
    const float* b_edge = (const float*)d_in[4];
    const float* w_root = (const float*)d_in[5];
    const float* b_conv = (const float*)d_in[6];
    const float* W1 = (const float*)d_in[7];
    const float* b1 = (const float*)d_in[8];
    const float* W2 = (const float*)d_in[9];
    const float* b2 = (const float*)d_in[10];
    const float* W3 = (const float*)d_in[11];
    const float* b3 = (const float*)d_in[12];
    float* out = (float*)d_out;

    const int N = in_sizes[0];
    const int E = in_sizes[2];
    const int G = N / NPG;
    const int* src = eidx;
    const int* dst = eidx + E;
    const int nquads = E / 4;

    // bucket sizing: target exactly 256 buckets (one per CU)
    const unsigned SZ = (unsigned)((N + 255) / 256);
    const int DB = (int)((N + SZ - 1) / SZ);
    const unsigned long long MAGIC = ((1ULL << 40) / SZ) + 1;

    const int hblocks = (G + HEAD_BLK - 1) / HEAD_BLK;
    char* ws = (char*)d_ws;

    const bool quadok = (E % 4) == 0 && DB <= DBMAX && DB >= 1 &&
                        SZ <= SZMAX && N < (1 << 23);
    const int  sbsz   = (N % NSB == 0) ? (N / NSB) : 0;

    const int NCH = (E + CH - 1) / CH;            // global chunk count
    const int bpx = (NCH + 7) / 8;

    // meta ints: histM8[NSB*NB1] | sseg[NSB+1] | gcntD[DBMAX] | gcurD[DBMAX] |
    //            bbaseD[DBMAX+1]
    const size_t META_INTS = (size_t)NSB * NB1 + (NSB + 1) + DBMAX + DBMAX + (DBMAX + 1);

    // v5 layout: recs (E*8) | pairs (NCH*CH*4) | ofsT (NCH*(DBMAX+1)*2) |
    //            nodes (N*4) | meta
    size_t off_pairs = (size_t)E * 8;
    size_t sz_pairs  = (size_t)NCH * CH * 4;
    size_t off_ofsT  = off_pairs + sz_pairs;
    size_t sz_ofsT   = ((size_t)NCH * (DBMAX + 1) * 2 + 15) & ~(size_t)15;
    size_t off_nodes = off_ofsT + sz_ofsT;
    size_t off_meta  = off_nodes + (size_t)N * 4;
    size_t need_v5   = off_meta + META_INTS * 4;

    // mid layout: pairs (E*4) | nodes | meta
    size_t off_nodes_mid = (size_t)E * 4;
    size_t off_meta_mid  = off_nodes_mid + (size_t)N * 4;
    size_t need_mid      = off_meta_mid + META_INTS * 4;

    if (quadok && sbsz > 0 && need_v5 <= ws_size) {
        v2u*            recs  = (v2u*)ws;
        unsigned*       pairs = (unsigned*)(ws + off_pairs);
        unsigned short* ofsT  = (unsigned short*)(ws + off_ofsT);
        float*          nodes = (float*)(ws + off_nodes);
        int*            meta  = (int*)(ws + off_meta);
        int* histM8 = meta;
        int* sseg   = meta + NSB * NB1;

        const int qpb = (nquads + NB1 - 1) / NB1;
        k_p1a<<<NB1, P1_THR, 0, stream>>>(src, nquads, qpb, sbsz, histM8);
        k_scanM<<<1, 512, 0, stream>>>(histM8, sseg);
        k_p1b<<<NB1, P1_THR, 0, stream>>>(src, dst, ea, w_edge, b_edge,
                                          nquads, qpb, sbsz, histM8, recs);
        k_p2<<<8 * bpx, P2_THR, 0, stream>>>(recs, x, sseg, sbsz, DB, NCH, bpx,
                                             E, SZ, MAGIC, ofsT, pairs);
        k_binB<<<DB, BB_THR, 0, stream>>>(pairs, ofsT, NCH, DB, SZ, x,
                                          w_root, b_conv, nodes, N);
        head_kernel<<<hblocks, HEAD_BLK, 0, stream>>>(nodes, W1, b1, W2, b2,
                                                      W3, b3, out, G);
    } else if (quadok && need_mid <= ws_size) {
        unsigned* pairs = (unsigned*)ws;
        float*    nodes = (float*)(ws + off_nodes_mid);
        int*      meta  = (int*)(ws + off_meta_mid);
        int* gcntD  = meta + NSB * NB1 + (NSB + 1);
        int* gcurD  = gcntD + DBMAX;
        int* bbaseD = gcurD + DBMAX;

        hipMemsetAsync(gcntD, 0, DBMAX * sizeof(int), stream);
        const int NBm = 2048;
        const int qpbm = (nquads + NBm - 1) / NBm;
        k_count_mid<<<NBm, 512, 0, stream>>>(dst, nquads, qpbm, DB, MAGIC, gcntD);
        k_scanD<<<1, 64, 0, stream>>>(gcntD, DB, bbaseD, gcurD);
        k_binA_resv<<<NBm, 512, 0, stream>>>(x, src, dst, ea, w_edge, b_edge,
                                             nquads, qpbm, DB, SZ, MAGIC,
                                             gcurD, pairs);
        k_binB_lin<<<DB, 1024, 0, stream>>>(pairs, bbaseD, SZ, x, w_root,
                                            b_conv, nodes, N);
        head_kernel<<<hblocks, HEAD_BLK, 0, stream>>>(nodes, W1, b1, W2, b2,
                                                      W3, b3, out, G);
    } else {
        float* agg   = (float*)d_ws;
        float* nodes = agg + N;
        hipMemsetAsync(agg, 0, (size_t)N * sizeof(float), stream);
        edge_kernel_atomic<<<2048, 256, 0, stream>>>(x, src, dst, ea, w_edge,
                                                     b_edge, agg, E);
        finalize_nodes<<<2048, 256, 0, stream>>>(x, agg, w_root, b_conv, nodes, N);
        head_kernel<<<hblocks, HEAD_BLK, 0, stream>>>(nodes, W1, b1, W2, b2,
                                                      W3, b3, out, G);
    }
}